// Round 5
// baseline (641.329 us; speedup 1.0000x reference)
//
#include <hip/hip_runtime.h>
#include <hip/hip_bf16.h>

// N=8192, D=512.  Q = emb@Wqk^T+bqk (K==Q); out = softmax(QK^T/sqrt(512)) @ V.
// Softmax rows sum to 1 => out = (softmax(S)@emb) @ Wv^T + bv (V never built).
// Device dtype runtime-detected (fp32 observed). Internal: bf16 MFMA, fp32 acc.
// R4 post-mortem: VGPR=56 -> serialized global loads (~21k cyc/iter). R5:
// source-batched load arrays (deep vmcnt pipelining), Plds double-buffer
// (1 barrier/iter), odd LDS strides (LDA 538, LDP 138) to kill 8-way conflicts.

#define NTOK 8192
#define DIM  512

typedef unsigned short ushort_t;
typedef __attribute__((ext_vector_type(8))) __bf16 bf16x8;
typedef __attribute__((ext_vector_type(4))) float f32x4;

__device__ __forceinline__ float bf2f(ushort_t u) {
    union { unsigned int i; float f; } v; v.i = ((unsigned int)u) << 16; return v.f;
}
__device__ __forceinline__ ushort_t f2bf(float f) {
    union { float f; unsigned int i; } v; v.f = f;
    unsigned int b = v.i;
    return (ushort_t)((b + 0x7FFFu + ((b >> 16) & 1u)) >> 16);   // RNE
}
__device__ __forceinline__ __bf16 f2bfh(float f) {
    union { ushort_t u; __bf16 h; } c; c.u = f2bf(f); return c.h;
}
__device__ __forceinline__ f32x4 mfma16(bf16x8 a, bf16x8 b, f32x4 c) {
    return __builtin_amdgcn_mfma_f32_16x16x32_bf16(a, b, c, 0, 0, 0);
}
__device__ __forceinline__ bf16x8 load8(const void* p, size_t idx, bool f32) {
    if (f32) {
        const float* f = (const float*)p + idx;
        bf16x8 r;
        #pragma unroll
        for (int j = 0; j < 8; ++j) r[j] = f2bfh(f[j]);
        return r;
    }
    return *(const bf16x8*)((const ushort_t*)p + idx);
}
__device__ __forceinline__ float loadS(const void* p, size_t idx, bool f32) {
    return f32 ? ((const float*)p)[idx] : bf2f(((const ushort_t*)p)[idx]);
}

#define LDA 538   // stride 269 dw ; 269%32=13 (odd) -> b128 row-reads spread banks
#define LDP 138   // stride  69 dw ;  69%32=5  (odd)

// ---------------------------------------------------------------------------
// Dtype probe: flag=1 => bf16 data, flag=0 => fp32.
// ---------------------------------------------------------------------------
__global__ void detect_kernel(const ushort_t* __restrict__ emb, int* __restrict__ flag)
{
    int lane = threadIdx.x;
    int cnt = 0;
    #pragma unroll
    for (int i = 0; i < 8; ++i) {
        ushort_t u = emb[(size_t)(lane * 8 + i) * 2];
        int a = u & 0x7FFF;
        int e = (u >> 7) & 0xFF;
        if (a == 0 || (e >= 111 && e <= 143)) cnt++;
    }
    cnt += __shfl_xor(cnt, 1);  cnt += __shfl_xor(cnt, 2);  cnt += __shfl_xor(cnt, 4);
    cnt += __shfl_xor(cnt, 8);  cnt += __shfl_xor(cnt, 16); cnt += __shfl_xor(cnt, 32);
    if (lane == 0) *flag = (cnt >= 460) ? 1 : 0;
}

// ---------------------------------------------------------------------------
// embT[512][8192] (bf16) = emb^T.
// ---------------------------------------------------------------------------
__global__ __launch_bounds__(256)
void transpose_kernel(const int* __restrict__ flag, const void* __restrict__ emb,
                      ushort_t* __restrict__ embT)
{
    __shared__ float tile[64][65];
    const bool f32 = (*flag == 0);
    const int t  = threadIdx.x;
    const int j0 = blockIdx.x * 64;
    const int d0 = blockIdx.y * 64;

    {
        int r = t >> 2, cs = (t & 3) * 16;
        if (f32) {
            const float* src = (const float*)emb + (size_t)(j0 + r) * DIM + d0 + cs;
            #pragma unroll
            for (int i = 0; i < 16; i += 4) {
                float4 v = *(const float4*)(src + i);
                tile[r][cs + i]     = v.x;
                tile[r][cs + i + 1] = v.y;
                tile[r][cs + i + 2] = v.z;
                tile[r][cs + i + 3] = v.w;
            }
        } else {
            const ushort_t* src = (const ushort_t*)emb + (size_t)(j0 + r) * DIM + d0 + cs;
            #pragma unroll
            for (int i = 0; i < 16; ++i) tile[r][cs + i] = bf2f(src[i]);
        }
    }
    __syncthreads();
    {
        int d = t >> 2, js = (t & 3) * 16;
        ushort_t buf[16];
        #pragma unroll
        for (int i = 0; i < 16; ++i) buf[i] = f2bf(tile[js + i][d]);
        ushort_t* dst = embT + (size_t)(d0 + d) * NTOK + j0 + js;
        *(uint4*)dst       = *(uint4*)&buf[0];
        *(uint4*)(dst + 8) = *(uint4*)&buf[8];
    }
}

// ---------------------------------------------------------------------------
// Q[8192][512](bf16, ws) = emb @ Wqk^T + bqk.  Batched B loads.
// ---------------------------------------------------------------------------
__global__ __launch_bounds__(512)
void projq_kernel(const int* __restrict__ flag, const void* __restrict__ emb,
                  const void* __restrict__ W, const void* __restrict__ bias,
                  ushort_t* __restrict__ C)
{
    __shared__ ushort_t Alds[32][LDA];
    const bool f32 = (*flag == 0);

    const int tid  = threadIdx.x;
    const int wave = tid >> 6;
    const int lane = tid & 63;
    const int quad = lane >> 4;
    const int col  = lane & 15;
    const int mblk = blockIdx.x * 32;

    #pragma unroll
    for (int i = 0; i < 4; ++i) {
        int chunk = i * 512 + tid;
        int row = chunk >> 6;
        int k8  = (chunk & 63) * 8;
        *(bf16x8*)&Alds[row][k8] = load8(emb, (size_t)(mblk + row) * 512 + k8, f32);
    }
    __syncthreads();

    f32x4 acc[2][4];
    #pragma unroll
    for (int r = 0; r < 2; ++r)
        #pragma unroll
        for (int c = 0; c < 4; ++c) acc[r][c] = (f32x4){0.f, 0.f, 0.f, 0.f};

    const int wcol = wave * 64;
    #pragma unroll
    for (int k4 = 0; k4 < 4; ++k4) {            // 4 kk per group
        bf16x8 wb[16];
        #pragma unroll
        for (int kk = 0; kk < 4; ++kk)
            #pragma unroll
            for (int c = 0; c < 4; ++c)
                wb[kk * 4 + c] = load8(W, (size_t)(wcol + c * 16 + col) * 512
                                          + (k4 * 4 + kk) * 32 + quad * 8, f32);
        #pragma unroll
        for (int kk = 0; kk < 4; ++kk) {
            bf16x8 a0 = *(const bf16x8*)&Alds[col][(k4 * 4 + kk) * 32 + quad * 8];
            bf16x8 a1 = *(const bf16x8*)&Alds[16 + col][(k4 * 4 + kk) * 32 + quad * 8];
            #pragma unroll
            for (int c = 0; c < 4; ++c) {
                acc[0][c] = mfma16(a0, wb[kk * 4 + c], acc[0][c]);
                acc[1][c] = mfma16(a1, wb[kk * 4 + c], acc[1][c]);
            }
        }
    }

    #pragma unroll
    for (int r = 0; r < 2; ++r)
        #pragma unroll
        for (int c = 0; c < 4; ++c)
            #pragma unroll
            for (int g = 0; g < 4; ++g) {
                int m = mblk + r * 16 + quad * 4 + g;
                int n = wcol + c * 16 + col;
                C[(size_t)m * DIM + n] = f2bf(acc[r][c][g] + loadS(bias, n, f32));
            }
}

// ---------------------------------------------------------------------------
// Fused attention + V-projection.  VT=1: embT fast path.  VT=0: gather fallback.
// 256 blocks x 512 thr; 32 Q-rows/block; 128-key tile; 1 barrier per iter
// (double-buffered Plds).  Load arrays force deep vmcnt pipelining.
// ---------------------------------------------------------------------------
template <int VT>
__global__ __launch_bounds__(512)
void attn_kernel(const int* __restrict__ flag, const ushort_t* __restrict__ Q,
                 const void* __restrict__ embOrT, const void* __restrict__ Wv,
                 const void* __restrict__ bv, void* __restrict__ Out)
{
    __shared__ ushort_t Qlds[32][LDA];      // Q tile; reused as T tile at end
    __shared__ ushort_t Plds[2][32][LDP];   // double-buffered P
    __shared__ float    Lpart[8][32];

    const bool f32 = (*flag == 0);
    const int tid  = threadIdx.x;
    const int wave = tid >> 6;
    const int lane = tid & 63;
    const int quad = lane >> 4;
    const int col  = lane & 15;
    const int q0   = blockIdx.x * 32;

    #pragma unroll
    for (int i = 0; i < 4; ++i) {
        int chunk = i * 512 + tid;
        int row = chunk >> 6;
        int k8  = (chunk & 63) * 8;
        *(bf16x8*)&Qlds[row][k8] = *(const bf16x8*)&Q[(size_t)(q0 + row) * 512 + k8];
    }
    __syncthreads();

    f32x4 accO[2][4];
    #pragma unroll
    for (int r = 0; r < 2; ++r)
        #pragma unroll
        for (int c = 0; c < 4; ++c) accO[r][c] = (f32x4){0.f, 0.f, 0.f, 0.f};

    float lsum[2][4];
    #pragma unroll
    for (int r = 0; r < 2; ++r)
        #pragma unroll
        for (int g = 0; g < 4; ++g) lsum[r][g] = 0.f;

    const float sc = 0.04419417382415922f * 1.4426950408889634f;  // 1/sqrt(512)*log2e
    const int wOcol = wave * 64;

    for (int it = 0; it < NTOK / 128; ++it) {
        const int j0  = it * 128;
        const int buf = it & 1;

        // ---- batched K-fragment loads (16 dwordx4 in flight) ----
        bf16x8 kb[16];
        const size_t keyrow = (size_t)(j0 + wave * 16 + col) * 512;
        #pragma unroll
        for (int kk = 0; kk < 16; ++kk)
            kb[kk] = *(const bf16x8*)&Q[keyrow + kk * 32 + quad * 8];

        // ---- S = Q_tile @ K_tile^T ----
        f32x4 accS[2];
        accS[0] = (f32x4){0.f, 0.f, 0.f, 0.f};
        accS[1] = (f32x4){0.f, 0.f, 0.f, 0.f};
        #pragma unroll
        for (int kk = 0; kk < 16; ++kk) {
            bf16x8 a0 = *(const bf16x8*)&Qlds[col][kk * 32 + quad * 8];
            bf16x8 a1 = *(const bf16x8*)&Qlds[16 + col][kk * 32 + quad * 8];
            accS[0] = mfma16(a0, kb[kk], accS[0]);
            accS[1] = mfma16(a1, kb[kk], accS[1]);
        }

        // ---- batched V-operand loads; latency overlaps exp+write+barrier ----
        bf16x8 vb[16];
        if (VT) {
            #pragma unroll
            for (int kk = 0; kk < 4; ++kk)
                #pragma unroll
                for (int c = 0; c < 4; ++c)
                    vb[kk * 4 + c] = *(const bf16x8*)((const ushort_t*)embOrT
                        + (size_t)(wOcol + c * 16 + col) * NTOK + j0 + kk * 32 + quad * 8);
        } else {
            #pragma unroll
            for (int kk = 0; kk < 4; ++kk)
                #pragma unroll
                for (int c = 0; c < 4; ++c) {
                    size_t base = (size_t)(j0 + kk * 32 + quad * 8) * 512 + (wOcol + c * 16 + col);
                    bf16x8 b;
                    if (f32) {
                        const float* bp = (const float*)embOrT + base;
                        #pragma unroll
                        for (int j = 0; j < 8; ++j) b[j] = f2bfh(bp[(size_t)j * 512]);
                    } else {
                        const __bf16* bp = (const __bf16*)embOrT + base;
                        #pragma unroll
                        for (int j = 0; j < 8; ++j) b[j] = bp[(size_t)j * 512];
                    }
                    vb[kk * 4 + c] = b;
                }
        }

        // ---- P = exp2(S*sc) -> Plds[buf] ----
        #pragma unroll
        for (int r = 0; r < 2; ++r)
            #pragma unroll
            for (int g = 0; g < 4; ++g) {
                float p = exp2f(fminf(accS[r][g] * sc, 126.0f));
                lsum[r][g] += p;
                Plds[buf][r * 16 + quad * 4 + g][wave * 16 + col] = f2bf(p);
            }

        __syncthreads();   // the ONLY barrier: P(t) visible; also protects
                           // buf reuse at distance 2 (reads(t) precede barrier(t+1))

        // ---- O += P @ V ----
        #pragma unroll
        for (int kk = 0; kk < 4; ++kk) {
            bf16x8 a0 = *(const bf16x8*)&Plds[buf][col][kk * 32 + quad * 8];
            bf16x8 a1 = *(const bf16x8*)&Plds[buf][16 + col][kk * 32 + quad * 8];
            #pragma unroll
            for (int c = 0; c < 4; ++c) {
                accO[0][c] = mfma16(a0, vb[kk * 4 + c], accO[0][c]);
                accO[1][c] = mfma16(a1, vb[kk * 4 + c], accO[1][c]);
            }
        }
    }

    // ---- softmax denominators ----
    #pragma unroll
    for (int r = 0; r < 2; ++r)
        #pragma unroll
        for (int g = 0; g < 4; ++g) {
            float s = lsum[r][g];
            s += __shfl_xor(s, 1);
            s += __shfl_xor(s, 2);
            s += __shfl_xor(s, 4);
            s += __shfl_xor(s, 8);
            lsum[r][g] = s;
        }
    if (col == 0) {
        #pragma unroll
        for (int r = 0; r < 2; ++r)
            #pragma unroll
            for (int g = 0; g < 4; ++g)
                Lpart[wave][r * 16 + quad * 4 + g] = lsum[r][g];
    }
    __syncthreads();   // Lpart ready; all waves past main loop (Qlds reusable)

    // ---- normalize, write T tile into Qlds ----
    #pragma unroll
    for (int r = 0; r < 2; ++r) {
        float rinv[4];
        #pragma unroll
        for (int g = 0; g < 4; ++g) {
            float t = 0.f;
            #pragma unroll
            for (int w = 0; w < 8; ++w) t += Lpart[w][r * 16 + quad * 4 + g];
            rinv[g] = 1.0f / t;
        }
        #pragma unroll
        for (int c = 0; c < 4; ++c)
            #pragma unroll
            for (int g = 0; g < 4; ++g)
                Qlds[r * 16 + quad * 4 + g][wOcol + c * 16 + col] = f2bf(accO[r][c][g] * rinv[g]);
    }
    __syncthreads();

    // ---- out = T @ Wv^T + bv (batched Wv loads) ----
    f32x4 acc2[2][4];
    #pragma unroll
    for (int r = 0; r < 2; ++r)
        #pragma unroll
        for (int c = 0; c < 4; ++c) acc2[r][c] = (f32x4){0.f, 0.f, 0.f, 0.f};

    #pragma unroll
    for (int k4 = 0; k4 < 4; ++k4) {
        bf16x8 wb[16];
        #pragma unroll
        for (int kk = 0; kk < 4; ++kk)
            #pragma unroll
            for (int c = 0; c < 4; ++c)
                wb[kk * 4 + c] = load8(Wv, (size_t)(wOcol + c * 16 + col) * 512
                                           + (k4 * 4 + kk) * 32 + quad * 8, f32);
        #pragma unroll
        for (int kk = 0; kk < 4; ++kk) {
            bf16x8 a0 = *(const bf16x8*)&Qlds[col][(k4 * 4 + kk) * 32 + quad * 8];
            bf16x8 a1 = *(const bf16x8*)&Qlds[16 + col][(k4 * 4 + kk) * 32 + quad * 8];
            #pragma unroll
            for (int c = 0; c < 4; ++c) {
                acc2[0][c] = mfma16(a0, wb[kk * 4 + c], acc2[0][c]);
                acc2[1][c] = mfma16(a1, wb[kk * 4 + c], acc2[1][c]);
            }
        }
    }

    #pragma unroll
    for (int r = 0; r < 2; ++r)
        #pragma unroll
        for (int c = 0; c < 4; ++c)
            #pragma unroll
            for (int g = 0; g < 4; ++g) {
                int m = q0 + r * 16 + quad * 4 + g;
                int n = wOcol + c * 16 + col;
                float v = acc2[r][c][g] + loadS(bv, n, f32);
                if (f32) ((float*)Out)[(size_t)m * DIM + n] = v;
                else     ((ushort_t*)Out)[(size_t)m * DIM + n] = f2bf(v);
            }
}

extern "C" void kernel_launch(void* const* d_in, const int* in_sizes, int n_in,
                              void* d_out, int out_size, void* d_ws, size_t ws_size,
                              hipStream_t stream)
{
    const void* emb = d_in[0];
    const void* Wqk = d_in[1];
    const void* bqk = d_in[2];
    const void* Wv  = d_in[3];
    const void* bv  = d_in[4];

    int*      flag = (int*)d_ws;
    ushort_t* embT = (ushort_t*)d_ws + 32;                       // offset 64 B
    ushort_t* Qws  = embT + (size_t)DIM * NTOK;                  // +8 MB

    const size_t need = 64 + 2 * (size_t)DIM * NTOK * 2;         // 16 MB + 64
    const bool fast = (ws_size >= need);

    detect_kernel<<<dim3(1), dim3(64), 0, stream>>>((const ushort_t*)emb, flag);
    if (fast) {
        transpose_kernel<<<dim3(NTOK / 64, DIM / 64), dim3(256), 0, stream>>>(flag, emb, embT);
        projq_kernel<<<dim3(NTOK / 32), dim3(512), 0, stream>>>(flag, emb, Wqk, bqk, Qws);
        attn_kernel<1><<<dim3(NTOK / 32), dim3(512), 0, stream>>>(flag, Qws, embT, Wv, bv, d_out);
    } else {
        ushort_t* Qsm = (ushort_t*)d_ws + 32;
        projq_kernel<<<dim3(NTOK / 32), dim3(512), 0, stream>>>(flag, emb, Wqk, bqk, Qsm);
        attn_kernel<0><<<dim3(NTOK / 32), dim3(512), 0, stream>>>(flag, Qsm, emb, Wv, bv, d_out);
    }
}

// Round 6
// 601.344 us; speedup vs baseline: 1.0665x; 1.0665x over previous
//
#include <hip/hip_runtime.h>
#include <hip/hip_bf16.h>

// N=8192, D=512.  Q = emb@Wqk^T+bqk (K==Q); out = softmax(QK^T/sqrt(512)) @ V.
// Softmax rows sum to 1 => out = (softmax(S)@emb) @ Wv^T + bv (V never built).
// Device dtype runtime-detected (fp32 observed). Internal: bf16 MFMA, fp32 acc.
// R5 post-mortem: 1 block/CU (2 waves/SIMD) made everything latency-bound;
// "odd" LDS strides regressed conflicts (b128 wants stride%32==4 dw uniform).
// R6: 1024-thread blocks (16 waves = 4/SIMD), key-tile 256, wave owns 16
// S-cols + 32 D-cols; strides back to %32==4 pattern.

#define NTOK 8192
#define DIM  512
#define KT   256          // keys per main-loop iteration
#define NW   16           // waves per block

typedef unsigned short ushort_t;
typedef __attribute__((ext_vector_type(8))) __bf16 bf16x8;
typedef __attribute__((ext_vector_type(4))) float f32x4;

__device__ __forceinline__ float bf2f(ushort_t u) {
    union { unsigned int i; float f; } v; v.i = ((unsigned int)u) << 16; return v.f;
}
__device__ __forceinline__ ushort_t f2bf(float f) {
    union { float f; unsigned int i; } v; v.f = f;
    unsigned int b = v.i;
    return (ushort_t)((b + 0x7FFFu + ((b >> 16) & 1u)) >> 16);   // RNE
}
__device__ __forceinline__ __bf16 f2bfh(float f) {
    union { ushort_t u; __bf16 h; } c; c.u = f2bf(f); return c.h;
}
__device__ __forceinline__ f32x4 mfma16(bf16x8 a, bf16x8 b, f32x4 c) {
    return __builtin_amdgcn_mfma_f32_16x16x32_bf16(a, b, c, 0, 0, 0);
}
__device__ __forceinline__ bf16x8 load8(const void* p, size_t idx, bool f32) {
    if (f32) {
        const float* f = (const float*)p + idx;
        bf16x8 r;
        #pragma unroll
        for (int j = 0; j < 8; ++j) r[j] = f2bfh(f[j]);
        return r;
    }
    return *(const bf16x8*)((const ushort_t*)p + idx);
}
__device__ __forceinline__ float loadS(const void* p, size_t idx, bool f32) {
    return f32 ? ((const float*)p)[idx] : bf2f(((const ushort_t*)p)[idx]);
}

// b128 row reads want stride%32 == 4 dw (uniform 2 dw/bank per 16-lane phase)
#define LDA 520   // 260 dw, 260%32 = 4
#define LDP 264   // 132 dw, 132%32 = 4  (KT=256 + 8 pad)

// ---------------------------------------------------------------------------
// Dtype probe: flag=1 => bf16 data, flag=0 => fp32.
// ---------------------------------------------------------------------------
__global__ void detect_kernel(const ushort_t* __restrict__ emb, int* __restrict__ flag)
{
    int lane = threadIdx.x;
    int cnt = 0;
    #pragma unroll
    for (int i = 0; i < 8; ++i) {
        ushort_t u = emb[(size_t)(lane * 8 + i) * 2];
        int a = u & 0x7FFF;
        int e = (u >> 7) & 0xFF;
        if (a == 0 || (e >= 111 && e <= 143)) cnt++;
    }
    cnt += __shfl_xor(cnt, 1);  cnt += __shfl_xor(cnt, 2);  cnt += __shfl_xor(cnt, 4);
    cnt += __shfl_xor(cnt, 8);  cnt += __shfl_xor(cnt, 16); cnt += __shfl_xor(cnt, 32);
    if (lane == 0) *flag = (cnt >= 460) ? 1 : 0;
}

// ---------------------------------------------------------------------------
// embT[512][8192] (bf16) = emb^T.
// ---------------------------------------------------------------------------
__global__ __launch_bounds__(256)
void transpose_kernel(const int* __restrict__ flag, const void* __restrict__ emb,
                      ushort_t* __restrict__ embT)
{
    __shared__ float tile[64][65];
    const bool f32 = (*flag == 0);
    const int t  = threadIdx.x;
    const int j0 = blockIdx.x * 64;
    const int d0 = blockIdx.y * 64;

    {
        int r = t >> 2, cs = (t & 3) * 16;
        if (f32) {
            const float* src = (const float*)emb + (size_t)(j0 + r) * DIM + d0 + cs;
            #pragma unroll
            for (int i = 0; i < 16; i += 4) {
                float4 v = *(const float4*)(src + i);
                tile[r][cs + i]     = v.x;
                tile[r][cs + i + 1] = v.y;
                tile[r][cs + i + 2] = v.z;
                tile[r][cs + i + 3] = v.w;
            }
        } else {
            const ushort_t* src = (const ushort_t*)emb + (size_t)(j0 + r) * DIM + d0 + cs;
            #pragma unroll
            for (int i = 0; i < 16; ++i) tile[r][cs + i] = bf2f(src[i]);
        }
    }
    __syncthreads();
    {
        int d = t >> 2, js = (t & 3) * 16;
        ushort_t buf[16];
        #pragma unroll
        for (int i = 0; i < 16; ++i) buf[i] = f2bf(tile[js + i][d]);
        ushort_t* dst = embT + (size_t)(d0 + d) * NTOK + j0 + js;
        *(uint4*)dst       = *(uint4*)&buf[0];
        *(uint4*)(dst + 8) = *(uint4*)&buf[8];
    }
}

// ---------------------------------------------------------------------------
// Q[8192][512](bf16, ws) = emb @ Wqk^T + bqk.  512 thr, 8 waves, 64 cols/wave.
// ---------------------------------------------------------------------------
__global__ __launch_bounds__(512)
void projq_kernel(const int* __restrict__ flag, const void* __restrict__ emb,
                  const void* __restrict__ W, const void* __restrict__ bias,
                  ushort_t* __restrict__ C)
{
    __shared__ ushort_t Alds[32][LDA];
    const bool f32 = (*flag == 0);

    const int tid  = threadIdx.x;
    const int wave = tid >> 6;
    const int lane = tid & 63;
    const int quad = lane >> 4;
    const int col  = lane & 15;
    const int mblk = blockIdx.x * 32;

    #pragma unroll
    for (int i = 0; i < 4; ++i) {
        int chunk = i * 512 + tid;
        int row = chunk >> 6;
        int k8  = (chunk & 63) * 8;
        *(bf16x8*)&Alds[row][k8] = load8(emb, (size_t)(mblk + row) * 512 + k8, f32);
    }
    __syncthreads();

    f32x4 acc[2][4];
    #pragma unroll
    for (int r = 0; r < 2; ++r)
        #pragma unroll
        for (int c = 0; c < 4; ++c) acc[r][c] = (f32x4){0.f, 0.f, 0.f, 0.f};

    const int wcol = wave * 64;
    #pragma unroll
    for (int kk = 0; kk < 16; ++kk) {
        bf16x8 a0 = *(const bf16x8*)&Alds[col][kk * 32 + quad * 8];
        bf16x8 a1 = *(const bf16x8*)&Alds[16 + col][kk * 32 + quad * 8];
        #pragma unroll
        for (int c = 0; c < 4; ++c) {
            bf16x8 b = load8(W, (size_t)(wcol + c * 16 + col) * 512 + kk * 32 + quad * 8, f32);
            acc[0][c] = mfma16(a0, b, acc[0][c]);
            acc[1][c] = mfma16(a1, b, acc[1][c]);
        }
    }

    #pragma unroll
    for (int r = 0; r < 2; ++r)
        #pragma unroll
        for (int c = 0; c < 4; ++c)
            #pragma unroll
            for (int g = 0; g < 4; ++g) {
                int m = mblk + r * 16 + quad * 4 + g;
                int n = wcol + c * 16 + col;
                C[(size_t)m * DIM + n] = f2bf(acc[r][c][g] + loadS(bias, n, f32));
            }
}

// ---------------------------------------------------------------------------
// Fused attention + V-projection.  1024 thr (16 waves = 4/SIMD), Tq=32,
// key-tile KT=256 (32 iters, 1 barrier each, double-buffered Plds).
// Wave w: computes S cols [16w,16w+16); owns D cols [32w,32w+32).
// VT=1: V-operand from embT (contiguous).  VT=0: gather fallback.
// ---------------------------------------------------------------------------
template <int VT>
__global__ __launch_bounds__(1024)
void attn_kernel(const int* __restrict__ flag, const ushort_t* __restrict__ Q,
                 const void* __restrict__ embOrT, const void* __restrict__ Wv,
                 const void* __restrict__ bv, void* __restrict__ Out)
{
    __shared__ ushort_t Qlds[32][LDA];       // 33,280 B; reused as T tile at end
    __shared__ ushort_t Plds[2][32][LDP];    // 33,792 B
    __shared__ float    Lpart[NW][32];       //  2,048 B

    const bool f32 = (*flag == 0);
    const int tid  = threadIdx.x;
    const int wave = tid >> 6;
    const int lane = tid & 63;
    const int quad = lane >> 4;
    const int col  = lane & 15;
    const int q0   = blockIdx.x * 32;

    #pragma unroll
    for (int i = 0; i < 2; ++i) {
        int chunk = i * 1024 + tid;
        int row = chunk >> 6;
        int k8  = (chunk & 63) * 8;
        *(bf16x8*)&Qlds[row][k8] = *(const bf16x8*)&Q[(size_t)(q0 + row) * 512 + k8];
    }
    __syncthreads();

    f32x4 accO[2][2];                    // 2 row-blocks x 2 col-frags (32 D-cols)
    #pragma unroll
    for (int r = 0; r < 2; ++r)
        #pragma unroll
        for (int c = 0; c < 2; ++c) accO[r][c] = (f32x4){0.f, 0.f, 0.f, 0.f};

    float lsum[2][4];
    #pragma unroll
    for (int r = 0; r < 2; ++r)
        #pragma unroll
        for (int g = 0; g < 4; ++g) lsum[r][g] = 0.f;

    const float sc = 0.04419417382415922f * 1.4426950408889634f;  // 1/sqrt(512)*log2e
    const int wOcol = wave * 32;

    for (int it = 0; it < NTOK / KT; ++it) {
        const int j0  = it * KT;
        const int buf = it & 1;

        // ---- K fragments: this wave's 16 keys, full 512 dims ----
        bf16x8 kb[16];
        const size_t keyrow = (size_t)(j0 + wave * 16 + col) * 512;
        #pragma unroll
        for (int kk = 0; kk < 16; ++kk)
            kb[kk] = *(const bf16x8*)&Q[keyrow + kk * 32 + quad * 8];

        // ---- S = Q_tile @ K_tile^T ----
        f32x4 accS[2];
        accS[0] = (f32x4){0.f, 0.f, 0.f, 0.f};
        accS[1] = (f32x4){0.f, 0.f, 0.f, 0.f};
        #pragma unroll
        for (int kk = 0; kk < 16; ++kk) {
            bf16x8 a0 = *(const bf16x8*)&Qlds[col][kk * 32 + quad * 8];
            bf16x8 a1 = *(const bf16x8*)&Qlds[16 + col][kk * 32 + quad * 8];
            accS[0] = mfma16(a0, kb[kk], accS[0]);
            accS[1] = mfma16(a1, kb[kk], accS[1]);
        }

        // ---- V-operand loads (latency overlaps exp + write + barrier) ----
        bf16x8 vb[16];                   // 8 kk x 2 col-frags
        if (VT) {
            #pragma unroll
            for (int kk = 0; kk < 8; ++kk)
                #pragma unroll
                for (int c = 0; c < 2; ++c)
                    vb[kk * 2 + c] = *(const bf16x8*)((const ushort_t*)embOrT
                        + (size_t)(wOcol + c * 16 + col) * NTOK + j0 + kk * 32 + quad * 8);
        } else {
            #pragma unroll
            for (int kk = 0; kk < 8; ++kk)
                #pragma unroll
                for (int c = 0; c < 2; ++c) {
                    size_t base = (size_t)(j0 + kk * 32 + quad * 8) * 512 + (wOcol + c * 16 + col);
                    bf16x8 b;
                    if (f32) {
                        const float* bp = (const float*)embOrT + base;
                        #pragma unroll
                        for (int j = 0; j < 8; ++j) b[j] = f2bfh(bp[(size_t)j * 512]);
                    } else {
                        const __bf16* bp = (const __bf16*)embOrT + base;
                        #pragma unroll
                        for (int j = 0; j < 8; ++j) b[j] = bp[(size_t)j * 512];
                    }
                    vb[kk * 2 + c] = b;
                }
        }

        // ---- P = exp2(S*sc) -> Plds[buf] ----
        #pragma unroll
        for (int r = 0; r < 2; ++r)
            #pragma unroll
            for (int g = 0; g < 4; ++g) {
                float p = exp2f(fminf(accS[r][g] * sc, 126.0f));
                lsum[r][g] += p;
                Plds[buf][r * 16 + quad * 4 + g][wave * 16 + col] = f2bf(p);
            }

        __syncthreads();   // P(t) visible; buf reuse at distance 2 is safe
                           // (reads of buf at t precede the barrier of t+1)

        // ---- O += P @ V ----
        #pragma unroll
        for (int kk = 0; kk < 8; ++kk) {
            bf16x8 a0 = *(const bf16x8*)&Plds[buf][col][kk * 32 + quad * 8];
            bf16x8 a1 = *(const bf16x8*)&Plds[buf][16 + col][kk * 32 + quad * 8];
            #pragma unroll
            for (int c = 0; c < 2; ++c) {
                accO[0][c] = mfma16(a0, vb[kk * 2 + c], accO[0][c]);
                accO[1][c] = mfma16(a1, vb[kk * 2 + c], accO[1][c]);
            }
        }
    }

    // ---- softmax denominators ----
    #pragma unroll
    for (int r = 0; r < 2; ++r)
        #pragma unroll
        for (int g = 0; g < 4; ++g) {
            float s = lsum[r][g];
            s += __shfl_xor(s, 1);
            s += __shfl_xor(s, 2);
            s += __shfl_xor(s, 4);
            s += __shfl_xor(s, 8);
            lsum[r][g] = s;
        }
    if (col == 0) {
        #pragma unroll
        for (int r = 0; r < 2; ++r)
            #pragma unroll
            for (int g = 0; g < 4; ++g)
                Lpart[wave][r * 16 + quad * 4 + g] = lsum[r][g];
    }
    __syncthreads();   // Lpart ready; all waves past main loop (Qlds reusable)

    // ---- normalize, write T tile into Qlds ----
    #pragma unroll
    for (int r = 0; r < 2; ++r) {
        float rinv[4];
        #pragma unroll
        for (int g = 0; g < 4; ++g) {
            float t = 0.f;
            #pragma unroll
            for (int w = 0; w < NW; ++w) t += Lpart[w][r * 16 + quad * 4 + g];
            rinv[g] = 1.0f / t;
        }
        #pragma unroll
        for (int c = 0; c < 2; ++c)
            #pragma unroll
            for (int g = 0; g < 4; ++g)
                Qlds[r * 16 + quad * 4 + g][wOcol + c * 16 + col] = f2bf(accO[r][c][g] * rinv[g]);
    }
    __syncthreads();

    // ---- out = T @ Wv^T + bv  (wave owns 32 out cols) ----
    f32x4 acc2[2][2];
    #pragma unroll
    for (int r = 0; r < 2; ++r)
        #pragma unroll
        for (int c = 0; c < 2; ++c) acc2[r][c] = (f32x4){0.f, 0.f, 0.f, 0.f};

    #pragma unroll
    for (int kk = 0; kk < 16; ++kk) {
        bf16x8 a0 = *(const bf16x8*)&Qlds[col][kk * 32 + quad * 8];
        bf16x8 a1 = *(const bf16x8*)&Qlds[16 + col][kk * 32 + quad * 8];
        #pragma unroll
        for (int c = 0; c < 2; ++c) {
            bf16x8 b = load8(Wv, (size_t)(wOcol + c * 16 + col) * 512 + kk * 32 + quad * 8, f32);
            acc2[0][c] = mfma16(a0, b, acc2[0][c]);
            acc2[1][c] = mfma16(a1, b, acc2[1][c]);
        }
    }

    #pragma unroll
    for (int r = 0; r < 2; ++r)
        #pragma unroll
        for (int c = 0; c < 2; ++c)
            #pragma unroll
            for (int g = 0; g < 4; ++g) {
                int m = q0 + r * 16 + quad * 4 + g;
                int n = wOcol + c * 16 + col;
                float v = acc2[r][c][g] + loadS(bv, n, f32);
                if (f32) ((float*)Out)[(size_t)m * DIM + n] = v;
                else     ((ushort_t*)Out)[(size_t)m * DIM + n] = f2bf(v);
            }
}

extern "C" void kernel_launch(void* const* d_in, const int* in_sizes, int n_in,
                              void* d_out, int out_size, void* d_ws, size_t ws_size,
                              hipStream_t stream)
{
    const void* emb = d_in[0];
    const void* Wqk = d_in[1];
    const void* bqk = d_in[2];
    const void* Wv  = d_in[3];
    const void* bv  = d_in[4];

    int*      flag = (int*)d_ws;
    ushort_t* embT = (ushort_t*)d_ws + 32;                       // offset 64 B
    ushort_t* Qws  = embT + (size_t)DIM * NTOK;                  // +8 MB

    const size_t need = 64 + 2 * (size_t)DIM * NTOK * 2;         // 16 MB + 64
    const bool fast = (ws_size >= need);

    detect_kernel<<<dim3(1), dim3(64), 0, stream>>>((const ushort_t*)emb, flag);
    if (fast) {
        transpose_kernel<<<dim3(NTOK / 64, DIM / 64), dim3(256), 0, stream>>>(flag, emb, embT);
        projq_kernel<<<dim3(NTOK / 32), dim3(512), 0, stream>>>(flag, emb, Wqk, bqk, Qws);
        attn_kernel<1><<<dim3(NTOK / 32), dim3(1024), 0, stream>>>(flag, Qws, embT, Wv, bv, d_out);
    } else {
        ushort_t* Qsm = (ushort_t*)d_ws + 32;
        projq_kernel<<<dim3(NTOK / 32), dim3(512), 0, stream>>>(flag, emb, Wqk, bqk, Qsm);
        attn_kernel<0><<<dim3(NTOK / 32), dim3(1024), 0, stream>>>(flag, Qsm, emb, Wv, bv, d_out);
    }
}

// Round 7
// 598.370 us; speedup vs baseline: 1.0718x; 1.0050x over previous
//
#include <hip/hip_runtime.h>
#include <hip/hip_bf16.h>

// N=8192, D=512.  Q = emb@Wqk^T+bqk (K==Q); out = softmax(QK^T/sqrt(512)) @ V.
// Softmax rows sum to 1 => out = (softmax(S)@emb) @ Wv^T + bv (V never built).
// Device dtype runtime-detected (fp32 observed). Internal: bf16 MFMA, fp32 acc.
// R6 post-mortem: R4/R5/R6 all pinned at ~7.5-8 TB/s cache traffic (4 GB/launch)
// => L3/fabric BW-bound, not latency-bound. R7: XCD-phased key sweep — blocks
// on the same XCD (blockIdx%8 heuristic) share a ~512KB/iter K+V window that
// fits the XCD's 4MB L2, converting fabric reads into local L2 hits.

#define NTOK 8192
#define DIM  512
#define KT   256          // keys per main-loop iteration
#define NW   16           // waves per block

typedef unsigned short ushort_t;
typedef __attribute__((ext_vector_type(8))) __bf16 bf16x8;
typedef __attribute__((ext_vector_type(4))) float f32x4;

__device__ __forceinline__ float bf2f(ushort_t u) {
    union { unsigned int i; float f; } v; v.i = ((unsigned int)u) << 16; return v.f;
}
__device__ __forceinline__ ushort_t f2bf(float f) {
    union { float f; unsigned int i; } v; v.f = f;
    unsigned int b = v.i;
    return (ushort_t)((b + 0x7FFFu + ((b >> 16) & 1u)) >> 16);   // RNE
}
__device__ __forceinline__ __bf16 f2bfh(float f) {
    union { ushort_t u; __bf16 h; } c; c.u = f2bf(f); return c.h;
}
__device__ __forceinline__ f32x4 mfma16(bf16x8 a, bf16x8 b, f32x4 c) {
    return __builtin_amdgcn_mfma_f32_16x16x32_bf16(a, b, c, 0, 0, 0);
}
__device__ __forceinline__ bf16x8 load8(const void* p, size_t idx, bool f32) {
    if (f32) {
        const float* f = (const float*)p + idx;
        bf16x8 r;
        #pragma unroll
        for (int j = 0; j < 8; ++j) r[j] = f2bfh(f[j]);
        return r;
    }
    return *(const bf16x8*)((const ushort_t*)p + idx);
}
__device__ __forceinline__ float loadS(const void* p, size_t idx, bool f32) {
    return f32 ? ((const float*)p)[idx] : bf2f(((const ushort_t*)p)[idx]);
}

// b128 row reads want stride%32 == 4 dw (uniform 2 dw/bank per 16-lane phase)
#define LDA 520   // 260 dw, 260%32 = 4
#define LDP 264   // 132 dw, 132%32 = 4  (KT=256 + 8 pad)

// ---------------------------------------------------------------------------
// Dtype probe: flag=1 => bf16 data, flag=0 => fp32.
// ---------------------------------------------------------------------------
__global__ void detect_kernel(const ushort_t* __restrict__ emb, int* __restrict__ flag)
{
    int lane = threadIdx.x;
    int cnt = 0;
    #pragma unroll
    for (int i = 0; i < 8; ++i) {
        ushort_t u = emb[(size_t)(lane * 8 + i) * 2];
        int a = u & 0x7FFF;
        int e = (u >> 7) & 0xFF;
        if (a == 0 || (e >= 111 && e <= 143)) cnt++;
    }
    cnt += __shfl_xor(cnt, 1);  cnt += __shfl_xor(cnt, 2);  cnt += __shfl_xor(cnt, 4);
    cnt += __shfl_xor(cnt, 8);  cnt += __shfl_xor(cnt, 16); cnt += __shfl_xor(cnt, 32);
    if (lane == 0) *flag = (cnt >= 460) ? 1 : 0;
}

// ---------------------------------------------------------------------------
// embT[512][8192] (bf16) = emb^T.
// ---------------------------------------------------------------------------
__global__ __launch_bounds__(256)
void transpose_kernel(const int* __restrict__ flag, const void* __restrict__ emb,
                      ushort_t* __restrict__ embT)
{
    __shared__ float tile[64][65];
    const bool f32 = (*flag == 0);
    const int t  = threadIdx.x;
    const int j0 = blockIdx.x * 64;
    const int d0 = blockIdx.y * 64;

    {
        int r = t >> 2, cs = (t & 3) * 16;
        if (f32) {
            const float* src = (const float*)emb + (size_t)(j0 + r) * DIM + d0 + cs;
            #pragma unroll
            for (int i = 0; i < 16; i += 4) {
                float4 v = *(const float4*)(src + i);
                tile[r][cs + i]     = v.x;
                tile[r][cs + i + 1] = v.y;
                tile[r][cs + i + 2] = v.z;
                tile[r][cs + i + 3] = v.w;
            }
        } else {
            const ushort_t* src = (const ushort_t*)emb + (size_t)(j0 + r) * DIM + d0 + cs;
            #pragma unroll
            for (int i = 0; i < 16; ++i) tile[r][cs + i] = bf2f(src[i]);
        }
    }
    __syncthreads();
    {
        int d = t >> 2, js = (t & 3) * 16;
        ushort_t buf[16];
        #pragma unroll
        for (int i = 0; i < 16; ++i) buf[i] = f2bf(tile[js + i][d]);
        ushort_t* dst = embT + (size_t)(d0 + d) * NTOK + j0 + js;
        *(uint4*)dst       = *(uint4*)&buf[0];
        *(uint4*)(dst + 8) = *(uint4*)&buf[8];
    }
}

// ---------------------------------------------------------------------------
// Q[8192][512](bf16, ws) = emb @ Wqk^T + bqk.  512 thr, 8 waves, 64 cols/wave.
// ---------------------------------------------------------------------------
__global__ __launch_bounds__(512)
void projq_kernel(const int* __restrict__ flag, const void* __restrict__ emb,
                  const void* __restrict__ W, const void* __restrict__ bias,
                  ushort_t* __restrict__ C)
{
    __shared__ ushort_t Alds[32][LDA];
    const bool f32 = (*flag == 0);

    const int tid  = threadIdx.x;
    const int wave = tid >> 6;
    const int lane = tid & 63;
    const int quad = lane >> 4;
    const int col  = lane & 15;
    const int mblk = blockIdx.x * 32;

    #pragma unroll
    for (int i = 0; i < 4; ++i) {
        int chunk = i * 512 + tid;
        int row = chunk >> 6;
        int k8  = (chunk & 63) * 8;
        *(bf16x8*)&Alds[row][k8] = load8(emb, (size_t)(mblk + row) * 512 + k8, f32);
    }
    __syncthreads();

    f32x4 acc[2][4];
    #pragma unroll
    for (int r = 0; r < 2; ++r)
        #pragma unroll
        for (int c = 0; c < 4; ++c) acc[r][c] = (f32x4){0.f, 0.f, 0.f, 0.f};

    const int wcol = wave * 64;
    #pragma unroll
    for (int kk = 0; kk < 16; ++kk) {
        bf16x8 a0 = *(const bf16x8*)&Alds[col][kk * 32 + quad * 8];
        bf16x8 a1 = *(const bf16x8*)&Alds[16 + col][kk * 32 + quad * 8];
        #pragma unroll
        for (int c = 0; c < 4; ++c) {
            bf16x8 b = load8(W, (size_t)(wcol + c * 16 + col) * 512 + kk * 32 + quad * 8, f32);
            acc[0][c] = mfma16(a0, b, acc[0][c]);
            acc[1][c] = mfma16(a1, b, acc[1][c]);
        }
    }

    #pragma unroll
    for (int r = 0; r < 2; ++r)
        #pragma unroll
        for (int c = 0; c < 4; ++c)
            #pragma unroll
            for (int g = 0; g < 4; ++g) {
                int m = mblk + r * 16 + quad * 4 + g;
                int n = wcol + c * 16 + col;
                C[(size_t)m * DIM + n] = f2bf(acc[r][c][g] + loadS(bias, n, f32));
            }
}

// ---------------------------------------------------------------------------
// Fused attention + V-projection.  1024 thr (16 waves = 4/SIMD), Tq=32,
// key-tile KT=256, XCD-phased key sweep: blocks with equal blockIdx%8
// (same-XCD heuristic) share a key window so K/V reads hit the XCD's L2.
// Wave w: computes S cols [16w,16w+16); owns D cols [32w,32w+32).
// ---------------------------------------------------------------------------
template <int VT>
__global__ __launch_bounds__(1024)
void attn_kernel(const int* __restrict__ flag, const ushort_t* __restrict__ Q,
                 const void* __restrict__ embOrT, const void* __restrict__ Wv,
                 const void* __restrict__ bv, void* __restrict__ Out)
{
    __shared__ ushort_t Qlds[32][LDA];       // 33,280 B; reused as T tile at end
    __shared__ ushort_t Plds[2][32][LDP];    // 33,792 B
    __shared__ float    Lpart[NW][32];       //  2,048 B

    const bool f32 = (*flag == 0);
    const int tid  = threadIdx.x;
    const int wave = tid >> 6;
    const int lane = tid & 63;
    const int quad = lane >> 4;
    const int col  = lane & 15;
    const int q0   = blockIdx.x * 32;

    #pragma unroll
    for (int i = 0; i < 2; ++i) {
        int chunk = i * 1024 + tid;
        int row = chunk >> 6;
        int k8  = (chunk & 63) * 8;
        *(bf16x8*)&Qlds[row][k8] = *(const bf16x8*)&Q[(size_t)(q0 + row) * 512 + k8];
    }
    __syncthreads();

    f32x4 accO[2][2];                    // 2 row-blocks x 2 col-frags (32 D-cols)
    #pragma unroll
    for (int r = 0; r < 2; ++r)
        #pragma unroll
        for (int c = 0; c < 2; ++c) accO[r][c] = (f32x4){0.f, 0.f, 0.f, 0.f};

    float lsum[2][4];
    #pragma unroll
    for (int r = 0; r < 2; ++r)
        #pragma unroll
        for (int g = 0; g < 4; ++g) lsum[r][g] = 0.f;

    const float sc = 0.04419417382415922f * 1.4426950408889634f;  // 1/sqrt(512)*log2e
    const int wOcol = wave * 32;

    // XCD-phased start: same-XCD blocks (blockIdx%8) share the key window.
    const int NITER = NTOK / KT;                     // 32
    const int it0   = (blockIdx.x & 7) * (NITER / 8); // 0,4,8,...,28

    for (int ii = 0; ii < NITER; ++ii) {
        const int it  = (it0 + ii) & (NITER - 1);
        const int j0  = it * KT;
        const int buf = ii & 1;

        // ---- K fragments: this wave's 16 keys, full 512 dims ----
        bf16x8 kb[16];
        const size_t keyrow = (size_t)(j0 + wave * 16 + col) * 512;
        #pragma unroll
        for (int kk = 0; kk < 16; ++kk)
            kb[kk] = *(const bf16x8*)&Q[keyrow + kk * 32 + quad * 8];

        // ---- S = Q_tile @ K_tile^T ----
        f32x4 accS[2];
        accS[0] = (f32x4){0.f, 0.f, 0.f, 0.f};
        accS[1] = (f32x4){0.f, 0.f, 0.f, 0.f};
        #pragma unroll
        for (int kk = 0; kk < 16; ++kk) {
            bf16x8 a0 = *(const bf16x8*)&Qlds[col][kk * 32 + quad * 8];
            bf16x8 a1 = *(const bf16x8*)&Qlds[16 + col][kk * 32 + quad * 8];
            accS[0] = mfma16(a0, kb[kk], accS[0]);
            accS[1] = mfma16(a1, kb[kk], accS[1]);
        }

        // ---- V-operand loads (latency overlaps exp + write + barrier) ----
        bf16x8 vb[16];                   // 8 kk x 2 col-frags
        if (VT) {
            #pragma unroll
            for (int kk = 0; kk < 8; ++kk)
                #pragma unroll
                for (int c = 0; c < 2; ++c)
                    vb[kk * 2 + c] = *(const bf16x8*)((const ushort_t*)embOrT
                        + (size_t)(wOcol + c * 16 + col) * NTOK + j0 + kk * 32 + quad * 8);
        } else {
            #pragma unroll
            for (int kk = 0; kk < 8; ++kk)
                #pragma unroll
                for (int c = 0; c < 2; ++c) {
                    size_t base = (size_t)(j0 + kk * 32 + quad * 8) * 512 + (wOcol + c * 16 + col);
                    bf16x8 b;
                    if (f32) {
                        const float* bp = (const float*)embOrT + base;
                        #pragma unroll
                        for (int j = 0; j < 8; ++j) b[j] = f2bfh(bp[(size_t)j * 512]);
                    } else {
                        const __bf16* bp = (const __bf16*)embOrT + base;
                        #pragma unroll
                        for (int j = 0; j < 8; ++j) b[j] = bp[(size_t)j * 512];
                    }
                    vb[kk * 2 + c] = b;
                }
        }

        // ---- P = exp2(S*sc) -> Plds[buf] ----
        #pragma unroll
        for (int r = 0; r < 2; ++r)
            #pragma unroll
            for (int g = 0; g < 4; ++g) {
                float p = exp2f(fminf(accS[r][g] * sc, 126.0f));
                lsum[r][g] += p;
                Plds[buf][r * 16 + quad * 4 + g][wave * 16 + col] = f2bf(p);
            }

        __syncthreads();   // P(t) visible; buf reuse at distance 2 is safe

        // ---- O += P @ V ----
        #pragma unroll
        for (int kk = 0; kk < 8; ++kk) {
            bf16x8 a0 = *(const bf16x8*)&Plds[buf][col][kk * 32 + quad * 8];
            bf16x8 a1 = *(const bf16x8*)&Plds[buf][16 + col][kk * 32 + quad * 8];
            #pragma unroll
            for (int c = 0; c < 2; ++c) {
                accO[0][c] = mfma16(a0, vb[kk * 2 + c], accO[0][c]);
                accO[1][c] = mfma16(a1, vb[kk * 2 + c], accO[1][c]);
            }
        }
    }

    // ---- softmax denominators ----
    #pragma unroll
    for (int r = 0; r < 2; ++r)
        #pragma unroll
        for (int g = 0; g < 4; ++g) {
            float s = lsum[r][g];
            s += __shfl_xor(s, 1);
            s += __shfl_xor(s, 2);
            s += __shfl_xor(s, 4);
            s += __shfl_xor(s, 8);
            lsum[r][g] = s;
        }
    if (col == 0) {
        #pragma unroll
        for (int r = 0; r < 2; ++r)
            #pragma unroll
            for (int g = 0; g < 4; ++g)
                Lpart[wave][r * 16 + quad * 4 + g] = lsum[r][g];
    }
    __syncthreads();   // Lpart ready; all waves past main loop (Qlds reusable)

    // ---- normalize, write T tile into Qlds ----
    #pragma unroll
    for (int r = 0; r < 2; ++r) {
        float rinv[4];
        #pragma unroll
        for (int g = 0; g < 4; ++g) {
            float t = 0.f;
            #pragma unroll
            for (int w = 0; w < NW; ++w) t += Lpart[w][r * 16 + quad * 4 + g];
            rinv[g] = 1.0f / t;
        }
        #pragma unroll
        for (int c = 0; c < 2; ++c)
            #pragma unroll
            for (int g = 0; g < 4; ++g)
                Qlds[r * 16 + quad * 4 + g][wOcol + c * 16 + col] = f2bf(accO[r][c][g] * rinv[g]);
    }
    __syncthreads();

    // ---- out = T @ Wv^T + bv  (wave owns 32 out cols) ----
    f32x4 acc2[2][2];
    #pragma unroll
    for (int r = 0; r < 2; ++r)
        #pragma unroll
        for (int c = 0; c < 2; ++c) acc2[r][c] = (f32x4){0.f, 0.f, 0.f, 0.f};

    #pragma unroll
    for (int kk = 0; kk < 16; ++kk) {
        bf16x8 a0 = *(const bf16x8*)&Qlds[col][kk * 32 + quad * 8];
        bf16x8 a1 = *(const bf16x8*)&Qlds[16 + col][kk * 32 + quad * 8];
        #pragma unroll
        for (int c = 0; c < 2; ++c) {
            bf16x8 b = load8(Wv, (size_t)(wOcol + c * 16 + col) * 512 + kk * 32 + quad * 8, f32);
            acc2[0][c] = mfma16(a0, b, acc2[0][c]);
            acc2[1][c] = mfma16(a1, b, acc2[1][c]);
        }
    }

    #pragma unroll
    for (int r = 0; r < 2; ++r)
        #pragma unroll
        for (int c = 0; c < 2; ++c)
            #pragma unroll
            for (int g = 0; g < 4; ++g) {
                int m = q0 + r * 16 + quad * 4 + g;
                int n = wOcol + c * 16 + col;
                float v = acc2[r][c][g] + loadS(bv, n, f32);
                if (f32) ((float*)Out)[(size_t)m * DIM + n] = v;
                else     ((ushort_t*)Out)[(size_t)m * DIM + n] = f2bf(v);
            }
}

extern "C" void kernel_launch(void* const* d_in, const int* in_sizes, int n_in,
                              void* d_out, int out_size, void* d_ws, size_t ws_size,
                              hipStream_t stream)
{
    const void* emb = d_in[0];
    const void* Wqk = d_in[1];
    const void* bqk = d_in[2];
    const void* Wv  = d_in[3];
    const void* bv  = d_in[4];

    int*      flag = (int*)d_ws;
    ushort_t* embT = (ushort_t*)d_ws + 32;                       // offset 64 B
    ushort_t* Qws  = embT + (size_t)DIM * NTOK;                  // +8 MB

    const size_t need = 64 + 2 * (size_t)DIM * NTOK * 2;         // 16 MB + 64
    const bool fast = (ws_size >= need);

    detect_kernel<<<dim3(1), dim3(64), 0, stream>>>((const ushort_t*)emb, flag);
    if (fast) {
        transpose_kernel<<<dim3(NTOK / 64, DIM / 64), dim3(256), 0, stream>>>(flag, emb, embT);
        projq_kernel<<<dim3(NTOK / 32), dim3(512), 0, stream>>>(flag, emb, Wqk, bqk, Qws);
        attn_kernel<1><<<dim3(NTOK / 32), dim3(1024), 0, stream>>>(flag, Qws, embT, Wv, bv, d_out);
    } else {
        ushort_t* Qsm = (ushort_t*)d_ws + 32;
        projq_kernel<<<dim3(NTOK / 32), dim3(512), 0, stream>>>(flag, emb, Wqk, bqk, Qsm);
        attn_kernel<0><<<dim3(NTOK / 32), dim3(1024), 0, stream>>>(flag, Qsm, emb, Wv, bv, d_out);
    }
}

// Round 8
// 519.606 us; speedup vs baseline: 1.2343x; 1.1516x over previous
//
#include <hip/hip_runtime.h>
#include <hip/hip_bf16.h>

// N=8192, D=512.  Q = emb@Wqk^T+bqk (K==Q); out = softmax(QK^T/sqrt(512)) @ V.
// Softmax rows sum to 1 => out = (softmax(S)@emb) @ Wv^T + bv (V never built).
// Device dtype runtime-detected (fp32 observed). Internal: bf16 MFMA, fp32 acc.
// R7 post-mortem: time tracks bytes-from-cache (~7.7 TB/s pin across R4-R7),
// insensitive to occupancy/order => traffic-bound. R8: Tq=64 + key-split-2
// halves unique traffic (4 GB -> 2 GB): 256 blocks = 128 q-tiles x 2 key
// halves, unnormalized O accumulated into fp32 d_out via device atomics,
// final kernel normalizes + fused Wv projection.

#define NTOK 8192
#define DIM  512
#define NW   16           // waves per attn block

typedef unsigned short ushort_t;
typedef __attribute__((ext_vector_type(8))) __bf16 bf16x8;
typedef __attribute__((ext_vector_type(4))) float f32x4;

__device__ __forceinline__ float bf2f(ushort_t u) {
    union { unsigned int i; float f; } v; v.i = ((unsigned int)u) << 16; return v.f;
}
__device__ __forceinline__ ushort_t f2bf(float f) {
    union { float f; unsigned int i; } v; v.f = f;
    unsigned int b = v.i;
    return (ushort_t)((b + 0x7FFFu + ((b >> 16) & 1u)) >> 16);   // RNE
}
__device__ __forceinline__ __bf16 f2bfh(float f) {
    union { ushort_t u; __bf16 h; } c; c.u = f2bf(f); return c.h;
}
__device__ __forceinline__ f32x4 mfma16(bf16x8 a, bf16x8 b, f32x4 c) {
    return __builtin_amdgcn_mfma_f32_16x16x32_bf16(a, b, c, 0, 0, 0);
}
__device__ __forceinline__ bf16x8 load8(const void* p, size_t idx, bool f32) {
    if (f32) {
        const float* f = (const float*)p + idx;
        bf16x8 r;
        #pragma unroll
        for (int j = 0; j < 8; ++j) r[j] = f2bfh(f[j]);
        return r;
    }
    return *(const bf16x8*)((const ushort_t*)p + idx);
}
__device__ __forceinline__ float loadS(const void* p, size_t idx, bool f32) {
    return f32 ? ((const float*)p)[idx] : bf2f(((const ushort_t*)p)[idx]);
}

// b128 row reads: stride%32 == 4 dw gives uniform 2 dw/bank per 16-lane phase
#define LDA 520   // 260 dw, %32 = 4
#define LDP 264   // 132 dw, %32 = 4

// ---------------------------------------------------------------------------
// Dtype probe: flag=1 => bf16 data, flag=0 => fp32.
// ---------------------------------------------------------------------------
__global__ void detect_kernel(const ushort_t* __restrict__ emb, int* __restrict__ flag)
{
    int lane = threadIdx.x;
    int cnt = 0;
    #pragma unroll
    for (int i = 0; i < 8; ++i) {
        ushort_t u = emb[(size_t)(lane * 8 + i) * 2];
        int a = u & 0x7FFF;
        int e = (u >> 7) & 0xFF;
        if (a == 0 || (e >= 111 && e <= 143)) cnt++;
    }
    cnt += __shfl_xor(cnt, 1);  cnt += __shfl_xor(cnt, 2);  cnt += __shfl_xor(cnt, 4);
    cnt += __shfl_xor(cnt, 8);  cnt += __shfl_xor(cnt, 16); cnt += __shfl_xor(cnt, 32);
    if (lane == 0) *flag = (cnt >= 460) ? 1 : 0;
}

// ---------------------------------------------------------------------------
// Zero d_out (fp32 accumulator) + lsum array.
// ---------------------------------------------------------------------------
__global__ __launch_bounds__(256)
void zero_kernel(float4* __restrict__ o, float4* __restrict__ l)
{
    size_t gid = (size_t)blockIdx.x * 256 + threadIdx.x;
    const float4 z = {0.f, 0.f, 0.f, 0.f};
    #pragma unroll
    for (int i = 0; i < 4; ++i) o[gid * 4 + i] = z;     // 262144 thr * 16 = 4M floats
    if (gid < 2048) l[gid] = z;                         // 8192 floats
}

// ---------------------------------------------------------------------------
// embT[512][8192] (bf16) = emb^T.
// ---------------------------------------------------------------------------
__global__ __launch_bounds__(256)
void transpose_kernel(const int* __restrict__ flag, const void* __restrict__ emb,
                      ushort_t* __restrict__ embT)
{
    __shared__ float tile[64][65];
    const bool f32 = (*flag == 0);
    const int t  = threadIdx.x;
    const int j0 = blockIdx.x * 64;
    const int d0 = blockIdx.y * 64;
    {
        int r = t >> 2, cs = (t & 3) * 16;
        if (f32) {
            const float* src = (const float*)emb + (size_t)(j0 + r) * DIM + d0 + cs;
            #pragma unroll
            for (int i = 0; i < 16; i += 4) {
                float4 v = *(const float4*)(src + i);
                tile[r][cs + i]     = v.x;
                tile[r][cs + i + 1] = v.y;
                tile[r][cs + i + 2] = v.z;
                tile[r][cs + i + 3] = v.w;
            }
        } else {
            const ushort_t* src = (const ushort_t*)emb + (size_t)(j0 + r) * DIM + d0 + cs;
            #pragma unroll
            for (int i = 0; i < 16; ++i) tile[r][cs + i] = bf2f(src[i]);
        }
    }
    __syncthreads();
    {
        int d = t >> 2, js = (t & 3) * 16;
        ushort_t buf[16];
        #pragma unroll
        for (int i = 0; i < 16; ++i) buf[i] = f2bf(tile[js + i][d]);
        ushort_t* dst = embT + (size_t)(d0 + d) * NTOK + j0 + js;
        *(uint4*)dst       = *(uint4*)&buf[0];
        *(uint4*)(dst + 8) = *(uint4*)&buf[8];
    }
}

// ---------------------------------------------------------------------------
// Q[8192][512](bf16, ws) = emb @ Wqk^T + bqk.  512 thr, 8 waves.
// ---------------------------------------------------------------------------
__global__ __launch_bounds__(512)
void projq_kernel(const int* __restrict__ flag, const void* __restrict__ emb,
                  const void* __restrict__ W, const void* __restrict__ bias,
                  ushort_t* __restrict__ C)
{
    __shared__ ushort_t Alds[32][LDA];
    const bool f32 = (*flag == 0);
    const int tid  = threadIdx.x;
    const int wave = tid >> 6;
    const int lane = tid & 63;
    const int quad = lane >> 4;
    const int col  = lane & 15;
    const int mblk = blockIdx.x * 32;

    #pragma unroll
    for (int i = 0; i < 4; ++i) {
        int chunk = i * 512 + tid;
        int row = chunk >> 6;
        int k8  = (chunk & 63) * 8;
        *(bf16x8*)&Alds[row][k8] = load8(emb, (size_t)(mblk + row) * 512 + k8, f32);
    }
    __syncthreads();

    f32x4 acc[2][4];
    #pragma unroll
    for (int r = 0; r < 2; ++r)
        #pragma unroll
        for (int c = 0; c < 4; ++c) acc[r][c] = (f32x4){0.f, 0.f, 0.f, 0.f};

    const int wcol = wave * 64;
    #pragma unroll
    for (int kk = 0; kk < 16; ++kk) {
        bf16x8 a0 = *(const bf16x8*)&Alds[col][kk * 32 + quad * 8];
        bf16x8 a1 = *(const bf16x8*)&Alds[16 + col][kk * 32 + quad * 8];
        #pragma unroll
        for (int c = 0; c < 4; ++c) {
            bf16x8 b = load8(W, (size_t)(wcol + c * 16 + col) * 512 + kk * 32 + quad * 8, f32);
            acc[0][c] = mfma16(a0, b, acc[0][c]);
            acc[1][c] = mfma16(a1, b, acc[1][c]);
        }
    }

    #pragma unroll
    for (int r = 0; r < 2; ++r)
        #pragma unroll
        for (int c = 0; c < 4; ++c)
            #pragma unroll
            for (int g = 0; g < 4; ++g) {
                int m = mblk + r * 16 + quad * 4 + g;
                int n = wcol + c * 16 + col;
                C[(size_t)m * DIM + n] = f2bf(acc[r][c][g] + loadS(bias, n, f32));
            }
}

// ---------------------------------------------------------------------------
// Attention partials: 256 blocks = 128 q-tiles (Tq=64) x 2 key-halves (4096).
// 1024 thr = 16 waves; KT=256/iter (16 iters). Wave w: keys [16w,16w+16) of
// the tile (full 64 rows), owns D cols [32w,32w+32) in PV.
// Unnormalized O += P@emb atomically into fp32 Oacc (=d_out); row sums l
// atomically into lsumG.  ks = blockIdx>>7 so co-resident blocks share keys.
// ---------------------------------------------------------------------------
__global__ __launch_bounds__(1024)
void attn_partial_kernel(const ushort_t* __restrict__ Q,
                         const ushort_t* __restrict__ embT,
                         float* __restrict__ Oacc, float* __restrict__ lsumG)
{
    __shared__ ushort_t Qlds[64][LDA];    // 66,560 B
    __shared__ ushort_t Plds[64][LDP];    // 33,792 B (single buffer, 2 barriers/iter)

    const int tid  = threadIdx.x;
    const int wave = tid >> 6;
    const int lane = tid & 63;
    const int quad = lane >> 4;
    const int col  = lane & 15;
    const int qt   = blockIdx.x & 127;
    const int ks   = blockIdx.x >> 7;       // key half
    const int q0   = qt * 64;
    const int kbase = ks * 4096;

    // stage Q tile 64x512 (bf16, 64 KB): 4096 chunks of 8, 1024 thr x 4
    #pragma unroll
    for (int i = 0; i < 4; ++i) {
        int chunk = i * 1024 + tid;
        int row = chunk >> 6;
        int k8  = (chunk & 63) * 8;
        *(bf16x8*)&Qlds[row][k8] = *(const bf16x8*)&Q[(size_t)(q0 + row) * 512 + k8];
    }
    __syncthreads();

    f32x4 accO[4][2];                 // 4 row-frags x 2 col-frags (32 D-cols)
    #pragma unroll
    for (int r = 0; r < 4; ++r)
        #pragma unroll
        for (int c = 0; c < 2; ++c) accO[r][c] = (f32x4){0.f, 0.f, 0.f, 0.f};

    float lsum[4][4];
    #pragma unroll
    for (int r = 0; r < 4; ++r)
        #pragma unroll
        for (int g = 0; g < 4; ++g) lsum[r][g] = 0.f;

    const float sc = 0.04419417382415922f * 1.4426950408889634f;  // 1/sqrt(512)*log2e
    const int wd = wave * 32;         // this wave's D-col base

    for (int it = 0; it < 16; ++it) {
        const int j0 = kbase + it * 256;

        // ---- K fragments: this wave's 16 keys x 512 dims ----
        bf16x8 kb[16];
        const size_t keyrow = (size_t)(j0 + wave * 16 + col) * 512;
        #pragma unroll
        for (int kk = 0; kk < 16; ++kk)
            kb[kk] = *(const bf16x8*)&Q[keyrow + kk * 32 + quad * 8];

        // ---- S(64 rows x 16 keys) = Q_tile @ K^T ----
        f32x4 accS[4];
        #pragma unroll
        for (int r = 0; r < 4; ++r) accS[r] = (f32x4){0.f, 0.f, 0.f, 0.f};
        #pragma unroll
        for (int kk = 0; kk < 16; ++kk) {
            #pragma unroll
            for (int r = 0; r < 4; ++r) {
                bf16x8 a = *(const bf16x8*)&Qlds[r * 16 + col][kk * 32 + quad * 8];
                accS[r] = mfma16(a, kb[kk], accS[r]);
            }
        }

        // ---- V-operand loads (latency hides under exp + barriers) ----
        bf16x8 vb[16];                // 8 kk x 2 col-frags, 256 keys x 32 dims
        #pragma unroll
        for (int kk = 0; kk < 8; ++kk)
            #pragma unroll
            for (int c = 0; c < 2; ++c)
                vb[kk * 2 + c] = *(const bf16x8*)&embT[
                    (size_t)(wd + c * 16 + col) * NTOK + j0 + kk * 32 + quad * 8];

        __syncthreads();   // previous iter's PV reads of Plds are done

        // ---- P = exp2(S*sc) -> Plds ----
        #pragma unroll
        for (int r = 0; r < 4; ++r)
            #pragma unroll
            for (int g = 0; g < 4; ++g) {
                float p = exp2f(fminf(accS[r][g] * sc, 126.0f));
                lsum[r][g] += p;
                Plds[r * 16 + quad * 4 + g][wave * 16 + col] = f2bf(p);
            }

        __syncthreads();   // P visible to all waves

        // ---- O += P @ V  (64 rows x this wave's 32 dims) ----
        #pragma unroll
        for (int kk = 0; kk < 8; ++kk) {
            #pragma unroll
            for (int r = 0; r < 4; ++r) {
                bf16x8 a = *(const bf16x8*)&Plds[r * 16 + col][kk * 32 + quad * 8];
                #pragma unroll
                for (int c = 0; c < 2; ++c)
                    accO[r][c] = mfma16(a, vb[kk * 2 + c], accO[r][c]);
            }
        }
    }

    // ---- merge: row sums (reduce over this wave's 16 key-lanes) ----
    #pragma unroll
    for (int r = 0; r < 4; ++r)
        #pragma unroll
        for (int g = 0; g < 4; ++g) {
            float s = lsum[r][g];
            s += __shfl_xor(s, 1);
            s += __shfl_xor(s, 2);
            s += __shfl_xor(s, 4);
            s += __shfl_xor(s, 8);
            if (col == 0)
                atomicAdd(&lsumG[q0 + r * 16 + quad * 4 + g], s);
        }

    // ---- merge: unnormalized O partial ----
    #pragma unroll
    for (int r = 0; r < 4; ++r)
        #pragma unroll
        for (int c = 0; c < 2; ++c)
            #pragma unroll
            for (int g = 0; g < 4; ++g) {
                int m = q0 + r * 16 + quad * 4 + g;
                int n = wd + c * 16 + col;
                atomicAdd(&Oacc[(size_t)m * DIM + n], accO[r][c][g]);
            }
}

// ---------------------------------------------------------------------------
// Final: out = (Oacc / l) @ Wv^T + bv, in place on d_out (row-local).
// 256 blocks x 512 thr, 32 rows/block.
// ---------------------------------------------------------------------------
__global__ __launch_bounds__(512)
void normproj_kernel(const int* __restrict__ flag, const float* __restrict__ lsumG,
                     const void* __restrict__ Wv, const void* __restrict__ bv,
                     void* __restrict__ Out)
{
    __shared__ ushort_t Alds[32][LDA];
    const bool f32 = (*flag == 0);
    const int tid  = threadIdx.x;
    const int wave = tid >> 6;
    const int lane = tid & 63;
    const int quad = lane >> 4;
    const int col  = lane & 15;
    const int mblk = blockIdx.x * 32;
    const float* Oacc = (const float*)Out;   // accumulated fp32 partials

    #pragma unroll
    for (int i = 0; i < 4; ++i) {
        int chunk = i * 512 + tid;
        int row = chunk >> 6;
        int k8  = (chunk & 63) * 8;
        float rv = 1.0f / lsumG[mblk + row];
        const float* src = Oacc + (size_t)(mblk + row) * 512 + k8;
        bf16x8 t;
        #pragma unroll
        for (int j = 0; j < 8; ++j) t[j] = f2bfh(src[j] * rv);
        *(bf16x8*)&Alds[row][k8] = t;
    }
    __syncthreads();

    f32x4 acc[2][4];
    #pragma unroll
    for (int r = 0; r < 2; ++r)
        #pragma unroll
        for (int c = 0; c < 4; ++c) acc[r][c] = (f32x4){0.f, 0.f, 0.f, 0.f};

    const int wcol = wave * 64;
    #pragma unroll
    for (int kk = 0; kk < 16; ++kk) {
        bf16x8 a0 = *(const bf16x8*)&Alds[col][kk * 32 + quad * 8];
        bf16x8 a1 = *(const bf16x8*)&Alds[16 + col][kk * 32 + quad * 8];
        #pragma unroll
        for (int c = 0; c < 4; ++c) {
            bf16x8 b = load8(Wv, (size_t)(wcol + c * 16 + col) * 512 + kk * 32 + quad * 8, f32);
            acc[0][c] = mfma16(a0, b, acc[0][c]);
            acc[1][c] = mfma16(a1, b, acc[1][c]);
        }
    }
    __syncthreads();   // all Oacc reads done before in-place writes

    #pragma unroll
    for (int r = 0; r < 2; ++r)
        #pragma unroll
        for (int c = 0; c < 4; ++c)
            #pragma unroll
            for (int g = 0; g < 4; ++g) {
                int m = mblk + r * 16 + quad * 4 + g;
                int n = wcol + c * 16 + col;
                float v = acc[r][c][g] + loadS(bv, n, f32);
                if (f32) ((float*)Out)[(size_t)m * DIM + n] = v;
                else     ((ushort_t*)Out)[(size_t)m * DIM + n] = f2bf(v);
            }
}

// ---------------------------------------------------------------------------
// Fallback fused attention (R6 structure) for smaller workspaces.
// ---------------------------------------------------------------------------
template <int VT>
__global__ __launch_bounds__(1024)
void attn_kernel(const int* __restrict__ flag, const ushort_t* __restrict__ Q,
                 const void* __restrict__ embOrT, const void* __restrict__ Wv,
                 const void* __restrict__ bv, void* __restrict__ Out)
{
    __shared__ ushort_t Qlds[32][LDA];
    __shared__ ushort_t Plds[2][32][LDP];
    __shared__ float    Lpart[NW][32];

    const bool f32 = (*flag == 0);
    const int tid  = threadIdx.x;
    const int wave = tid >> 6;
    const int lane = tid & 63;
    const int quad = lane >> 4;
    const int col  = lane & 15;
    const int q0   = blockIdx.x * 32;

    #pragma unroll
    for (int i = 0; i < 2; ++i) {
        int chunk = i * 1024 + tid;
        int row = chunk >> 6;
        int k8  = (chunk & 63) * 8;
        *(bf16x8*)&Qlds[row][k8] = *(const bf16x8*)&Q[(size_t)(q0 + row) * 512 + k8];
    }
    __syncthreads();

    f32x4 accO[2][2];
    #pragma unroll
    for (int r = 0; r < 2; ++r)
        #pragma unroll
        for (int c = 0; c < 2; ++c) accO[r][c] = (f32x4){0.f, 0.f, 0.f, 0.f};

    float lsum[2][4];
    #pragma unroll
    for (int r = 0; r < 2; ++r)
        #pragma unroll
        for (int g = 0; g < 4; ++g) lsum[r][g] = 0.f;

    const float sc = 0.04419417382415922f * 1.4426950408889634f;
    const int wOcol = wave * 32;

    for (int it = 0; it < 32; ++it) {
        const int j0  = it * 256;
        const int buf = it & 1;

        bf16x8 kb[16];
        const size_t keyrow = (size_t)(j0 + wave * 16 + col) * 512;
        #pragma unroll
        for (int kk = 0; kk < 16; ++kk)
            kb[kk] = *(const bf16x8*)&Q[keyrow + kk * 32 + quad * 8];

        f32x4 accS[2];
        accS[0] = (f32x4){0.f, 0.f, 0.f, 0.f};
        accS[1] = (f32x4){0.f, 0.f, 0.f, 0.f};
        #pragma unroll
        for (int kk = 0; kk < 16; ++kk) {
            bf16x8 a0 = *(const bf16x8*)&Qlds[col][kk * 32 + quad * 8];
            bf16x8 a1 = *(const bf16x8*)&Qlds[16 + col][kk * 32 + quad * 8];
            accS[0] = mfma16(a0, kb[kk], accS[0]);
            accS[1] = mfma16(a1, kb[kk], accS[1]);
        }

        bf16x8 vb[16];
        if (VT) {
            #pragma unroll
            for (int kk = 0; kk < 8; ++kk)
                #pragma unroll
                for (int c = 0; c < 2; ++c)
                    vb[kk * 2 + c] = *(const bf16x8*)((const ushort_t*)embOrT
                        + (size_t)(wOcol + c * 16 + col) * NTOK + j0 + kk * 32 + quad * 8);
        } else {
            #pragma unroll
            for (int kk = 0; kk < 8; ++kk)
                #pragma unroll
                for (int c = 0; c < 2; ++c) {
                    size_t base = (size_t)(j0 + kk * 32 + quad * 8) * 512 + (wOcol + c * 16 + col);
                    bf16x8 b;
                    if (f32) {
                        const float* bp = (const float*)embOrT + base;
                        #pragma unroll
                        for (int j = 0; j < 8; ++j) b[j] = f2bfh(bp[(size_t)j * 512]);
                    } else {
                        const __bf16* bp = (const __bf16*)embOrT + base;
                        #pragma unroll
                        for (int j = 0; j < 8; ++j) b[j] = bp[(size_t)j * 512];
                    }
                    vb[kk * 2 + c] = b;
                }
        }

        #pragma unroll
        for (int r = 0; r < 2; ++r)
            #pragma unroll
            for (int g = 0; g < 4; ++g) {
                float p = exp2f(fminf(accS[r][g] * sc, 126.0f));
                lsum[r][g] += p;
                Plds[buf][r * 16 + quad * 4 + g][wave * 16 + col] = f2bf(p);
            }

        __syncthreads();

        #pragma unroll
        for (int kk = 0; kk < 8; ++kk) {
            bf16x8 a0 = *(const bf16x8*)&Plds[buf][col][kk * 32 + quad * 8];
            bf16x8 a1 = *(const bf16x8*)&Plds[buf][16 + col][kk * 32 + quad * 8];
            #pragma unroll
            for (int c = 0; c < 2; ++c) {
                accO[0][c] = mfma16(a0, vb[kk * 2 + c], accO[0][c]);
                accO[1][c] = mfma16(a1, vb[kk * 2 + c], accO[1][c]);
            }
        }
    }

    #pragma unroll
    for (int r = 0; r < 2; ++r)
        #pragma unroll
        for (int g = 0; g < 4; ++g) {
            float s = lsum[r][g];
            s += __shfl_xor(s, 1);
            s += __shfl_xor(s, 2);
            s += __shfl_xor(s, 4);
            s += __shfl_xor(s, 8);
            lsum[r][g] = s;
        }
    if (col == 0) {
        #pragma unroll
        for (int r = 0; r < 2; ++r)
            #pragma unroll
            for (int g = 0; g < 4; ++g)
                Lpart[wave][r * 16 + quad * 4 + g] = lsum[r][g];
    }
    __syncthreads();

    #pragma unroll
    for (int r = 0; r < 2; ++r) {
        float rinv[4];
        #pragma unroll
        for (int g = 0; g < 4; ++g) {
            float t = 0.f;
            #pragma unroll
            for (int w = 0; w < NW; ++w) t += Lpart[w][r * 16 + quad * 4 + g];
            rinv[g] = 1.0f / t;
        }
        #pragma unroll
        for (int c = 0; c < 2; ++c)
            #pragma unroll
            for (int g = 0; g < 4; ++g)
                Qlds[r * 16 + quad * 4 + g][wOcol + c * 16 + col] = f2bf(accO[r][c][g] * rinv[g]);
    }
    __syncthreads();

    f32x4 acc2[2][2];
    #pragma unroll
    for (int r = 0; r < 2; ++r)
        #pragma unroll
        for (int c = 0; c < 2; ++c) acc2[r][c] = (f32x4){0.f, 0.f, 0.f, 0.f};

    #pragma unroll
    for (int kk = 0; kk < 16; ++kk) {
        bf16x8 a0 = *(const bf16x8*)&Qlds[col][kk * 32 + quad * 8];
        bf16x8 a1 = *(const bf16x8*)&Qlds[16 + col][kk * 32 + quad * 8];
        #pragma unroll
        for (int c = 0; c < 2; ++c) {
            bf16x8 b = load8(Wv, (size_t)(wOcol + c * 16 + col) * 512 + kk * 32 + quad * 8, f32);
            acc2[0][c] = mfma16(a0, b, acc2[0][c]);
            acc2[1][c] = mfma16(a1, b, acc2[1][c]);
        }
    }

    #pragma unroll
    for (int r = 0; r < 2; ++r)
        #pragma unroll
        for (int c = 0; c < 2; ++c)
            #pragma unroll
            for (int g = 0; g < 4; ++g) {
                int m = q0 + r * 16 + quad * 4 + g;
                int n = wOcol + c * 16 + col;
                float v = acc2[r][c][g] + loadS(bv, n, f32);
                if (f32) ((float*)Out)[(size_t)m * DIM + n] = v;
                else     ((ushort_t*)Out)[(size_t)m * DIM + n] = f2bf(v);
            }
}

extern "C" void kernel_launch(void* const* d_in, const int* in_sizes, int n_in,
                              void* d_out, int out_size, void* d_ws, size_t ws_size,
                              hipStream_t stream)
{
    const void* emb = d_in[0];
    const void* Wqk = d_in[1];
    const void* bqk = d_in[2];
    const void* Wv  = d_in[3];
    const void* bv  = d_in[4];

    const size_t QB = (size_t)NTOK * DIM * 2;            // 8 MB bf16

    int*      flag = (int*)d_ws;
    float*    lsumG = (float*)((char*)d_ws + 64);        // 32 KB
    ushort_t* embT = (ushort_t*)((char*)d_ws + 64 + NTOK * 4);
    ushort_t* Qws  = embT + (size_t)DIM * NTOK;

    const size_t need3 = 64 + NTOK * 4 + 2 * QB;         // atomic-merge path
    const size_t need2 = 64 + 2 * QB;                    // R6 fast path

    detect_kernel<<<dim3(1), dim3(64), 0, stream>>>((const ushort_t*)emb, flag);

    if (ws_size >= need3) {
        transpose_kernel<<<dim3(NTOK / 64, DIM / 64), dim3(256), 0, stream>>>(flag, emb, embT);
        projq_kernel<<<dim3(NTOK / 32), dim3(512), 0, stream>>>(flag, emb, Wqk, bqk, Qws);
        zero_kernel<<<dim3(1024), dim3(256), 0, stream>>>((float4*)d_out, (float4*)lsumG);
        attn_partial_kernel<<<dim3(256), dim3(1024), 0, stream>>>(Qws, embT,
                                                                  (float*)d_out, lsumG);
        normproj_kernel<<<dim3(NTOK / 32), dim3(512), 0, stream>>>(flag, lsumG, Wv, bv, d_out);
    } else if (ws_size >= need2) {
        ushort_t* embT2 = (ushort_t*)((char*)d_ws + 64);
        ushort_t* Qws2  = embT2 + (size_t)DIM * NTOK;
        transpose_kernel<<<dim3(NTOK / 64, DIM / 64), dim3(256), 0, stream>>>(flag, emb, embT2);
        projq_kernel<<<dim3(NTOK / 32), dim3(512), 0, stream>>>(flag, emb, Wqk, bqk, Qws2);
        attn_kernel<1><<<dim3(NTOK / 32), dim3(1024), 0, stream>>>(flag, Qws2, embT2, Wv, bv, d_out);
    } else {
        ushort_t* Qsm = (ushort_t*)((char*)d_ws + 64);
        projq_kernel<<<dim3(NTOK / 32), dim3(512), 0, stream>>>(flag, emb, Wqk, bqk, Qsm);
        attn_kernel<0><<<dim3(NTOK / 32), dim3(1024), 0, stream>>>(flag, Qsm, emb, Wv, bv, d_out);
    }
}